// Round 6
// baseline (1257.672 us; speedup 1.0000x reference)
//
#include <hip/hip_runtime.h>
#include <hip/hip_fp16.h>
#include <hip/hip_cooperative_groups.h>

namespace cg = cooperative_groups;

#define NN 512
#define HROWS 256          // rows per block (half matrix)
#define WAVES 8            // 512 threads
#define RREG 16            // register-resident rows per wave (128 total)
#define RLDS 16            // LDS-resident rows per wave (128 total)
#define NITER 10

union H2U { uint32_t u; __half2 h; };

__device__ __forceinline__ float wave_reduce_sum(float v) {
    #pragma unroll
    for (int off = 32; off > 0; off >>= 1)
        v += __shfl_xor(v, off, 64);
    return v;   // all 64 lanes hold the sum
}

__device__ __forceinline__ uint4 pack8(const float e[8]) {
    H2U a, b, c, d;
    a.h = __floats2half2_rn(e[0], e[1]);
    b.h = __floats2half2_rn(e[2], e[3]);
    c.h = __floats2half2_rn(e[4], e[5]);
    d.h = __floats2half2_rn(e[6], e[7]);
    return make_uint4(a.u, b.u, c.u, d.u);
}

__device__ __forceinline__ void unpack8(uint4 q, float e[8]) {
    H2U u; float2 f;
    u.u = q.x; f = __half22float2(u.h); e[0] = f.x; e[1] = f.y;
    u.u = q.y; f = __half22float2(u.h); e[2] = f.x; e[3] = f.y;
    u.u = q.z; f = __half22float2(u.h); e[4] = f.x; e[5] = f.y;
    u.u = q.w; f = __half22float2(u.h); e[6] = f.x; e[7] = f.y;
}

// Hybrid E residency (R2-R5 lesson: big per-thread arrays go to scratch and
// the allocator refuses >128 VGPRs; LDS/CU=160KB is the reliable on-CU store).
// Per block: 256 rows of E=exp(S). Rows 0..127: 16 NAMED uint4 regs/thread
// (no array => no SROA failure). Rows 128..255: packed fp16 in LDS (128 KB).
// Fused sweep per iteration: A_i = 1/dot(E_i,B) (wave butterfly), col
// partials c_j += E_ij*A_i; col sums completed by pairwise partner exchange
// through global ws with release/acquire flags (commutative sum => both
// blocks compute identical Bv => deterministic).
#define E_ROWS(M) M(0) M(1) M(2) M(3) M(4) M(5) M(6) M(7) \
                  M(8) M(9) M(10) M(11) M(12) M(13) M(14) M(15)

__global__ __launch_bounds__(512)
__attribute__((amdgpu_waves_per_eu(2, 2)))
void sinkhorn_pair(const float* __restrict__ Sg,
                   float* __restrict__ outg,
                   int* __restrict__ flags,
                   float* __restrict__ xdata,
                   int nmat) {
    cg::grid_group grid = cg::this_grid();

    const int blk  = blockIdx.x;
    const int mat  = blk % nmat;
    const int half = blk / nmat;           // partner (1-half)*nmat+mat: same XCD under %8 dispatch
    const size_t base = (size_t)mat * NN * NN + (size_t)half * HROWS * NN;
    const float* S = Sg + base;
    float* out = outg + base;

    __shared__ uint32_t Elds[128][NN / 2]; // fp16x2-packed E rows 128..255 (128 KB)
    __shared__ float part[WAVES][NN];      // per-wave col partials (16 KB)
    __shared__ float Bv[NN];               // 1/col-sums
    __shared__ float Av[HROWS];            // 1/row-sums

    const int tid  = threadIdx.x;
    const int lane = tid & 63;
    const int w    = tid >> 6;

    // ---- reset partner flags (ws is NOT re-poisoned between graph replays) ----
    if (tid < NITER)
        flags[(tid * 2 + half) * nmat + mat] = 0;
    __threadfence();
    grid.sync();

    #define DECL_E(rr) uint4 E##rr;
    E_ROWS(DECL_E)
    #undef DECL_E

    float c[8] = {0.f, 0.f, 0.f, 0.f, 0.f, 0.f, 0.f, 0.f};

    // ---- sweep 0: E = exp(S); A = 1/rowsum (B=1); col partials with A ----
    #define PASS0_BODY(lr, STORE) { \
        const float4* p = reinterpret_cast<const float4*>(S + (size_t)(lr) * NN + lane * 8); \
        float4 x0 = p[0], x1 = p[1]; \
        float e[8]; \
        e[0] = __expf(x0.x); e[1] = __expf(x0.y); e[2] = __expf(x0.z); e[3] = __expf(x0.w); \
        e[4] = __expf(x1.x); e[5] = __expf(x1.y); e[6] = __expf(x1.z); e[7] = __expf(x1.w); \
        STORE; \
        float rs = wave_reduce_sum(((e[0]+e[1])+(e[2]+e[3]))+((e[4]+e[5])+(e[6]+e[7]))); \
        const float a = 1.0f / rs; \
        if (lane == 0) Av[lr] = a; \
        c[0] += e[0]*a; c[1] += e[1]*a; c[2] += e[2]*a; c[3] += e[3]*a; \
        c[4] += e[4]*a; c[5] += e[5]*a; c[6] += e[6]*a; c[7] += e[7]*a; }

    #define PASS0_REG(rr) PASS0_BODY(w * RREG + rr, E##rr = pack8(e))
    E_ROWS(PASS0_REG)
    #undef PASS0_REG

    #pragma unroll
    for (int rr = 0; rr < RLDS; ++rr) {
        const int lrl = w * RLDS + rr;     // 0..127
        PASS0_BODY(128 + lrl,
                   *reinterpret_cast<uint4*>(&Elds[lrl][lane * 4]) = pack8(e))
    }
    #undef PASS0_BODY

    // ---- per-iteration: complete col sums via partner exchange -> Bv ----
    for (int t = 0; t < NITER; ++t) {
        *reinterpret_cast<float4*>(&part[w][lane * 8])     = make_float4(c[0], c[1], c[2], c[3]);
        *reinterpret_cast<float4*>(&part[w][lane * 8 + 4]) = make_float4(c[4], c[5], c[6], c[7]);
        __syncthreads();

        float mine = 0.f;
        #pragma unroll
        for (int k = 0; k < WAVES; ++k) mine += part[k][tid];

        const int myslot = (t * 2 + half) * nmat + mat;
        const int pfslot = (t * 2 + (1 - half)) * nmat + mat;
        xdata[(size_t)myslot * NN + tid] = mine;
        __threadfence();
        __syncthreads();
        if (tid == 0)
            __hip_atomic_store(&flags[myslot], 1, __ATOMIC_RELEASE, __HIP_MEMORY_SCOPE_AGENT);
        while (__hip_atomic_load(&flags[pfslot], __ATOMIC_ACQUIRE, __HIP_MEMORY_SCOPE_AGENT) == 0) {}
        const float theirs = xdata[(size_t)pfslot * NN + tid];
        Bv[tid] = 1.0f / (mine + theirs);   // commutative -> identical in both blocks
        __syncthreads();

        if (t == NITER - 1) break;          // B^(9) done; A^(9) already in Av

        // ---- fused sweep t+1: A_i = 1/dot(E_i, B); c_j += E_ij * A_i ----
        float b[8];
        #pragma unroll
        for (int k = 0; k < 8; ++k) b[k] = Bv[lane * 8 + k];
        #pragma unroll
        for (int k = 0; k < 8; ++k) c[k] = 0.f;

        #define SWEEP_BODY(lr, LOADQ) { \
            uint4 q = (LOADQ); \
            float e[8]; unpack8(q, e); \
            float d = ((e[0]*b[0] + e[1]*b[1]) + (e[2]*b[2] + e[3]*b[3])) + \
                      ((e[4]*b[4] + e[5]*b[5]) + (e[6]*b[6] + e[7]*b[7])); \
            d = wave_reduce_sum(d); \
            const float a = 1.0f / d; \
            if (lane == 0) Av[lr] = a; \
            c[0] += e[0]*a; c[1] += e[1]*a; c[2] += e[2]*a; c[3] += e[3]*a; \
            c[4] += e[4]*a; c[5] += e[5]*a; c[6] += e[6]*a; c[7] += e[7]*a; }

        #define SWEEP_REG(rr) SWEEP_BODY(w * RREG + rr, E##rr)
        E_ROWS(SWEEP_REG)
        #undef SWEEP_REG

        #pragma unroll
        for (int rr = 0; rr < RLDS; ++rr) {
            const int lrl = w * RLDS + rr;
            SWEEP_BODY(128 + lrl,
                       *reinterpret_cast<const uint4*>(&Elds[lrl][lane * 4]))
        }
        #undef SWEEP_BODY
        __syncthreads();
    }

    // ---- final: out_ij = E_ij * A_i * B_j ----
    {
        float b[8];
        #pragma unroll
        for (int k = 0; k < 8; ++k) b[k] = Bv[lane * 8 + k];

        #define FINAL_BODY(lr, LOADQ) { \
            uint4 q = (LOADQ); \
            float e[8]; unpack8(q, e); \
            const float a = Av[lr]; \
            float* op = out + (size_t)(lr) * NN + lane * 8; \
            reinterpret_cast<float4*>(op)[0] = \
                make_float4(e[0]*a*b[0], e[1]*a*b[1], e[2]*a*b[2], e[3]*a*b[3]); \
            reinterpret_cast<float4*>(op)[1] = \
                make_float4(e[4]*a*b[4], e[5]*a*b[5], e[6]*a*b[6], e[7]*a*b[7]); }

        #define FINAL_REG(rr) FINAL_BODY(w * RREG + rr, E##rr)
        E_ROWS(FINAL_REG)
        #undef FINAL_REG

        #pragma unroll
        for (int rr = 0; rr < RLDS; ++rr) {
            const int lrl = w * RLDS + rr;
            FINAL_BODY(128 + lrl,
                       *reinterpret_cast<const uint4*>(&Elds[lrl][lane * 4]))
        }
        #undef FINAL_BODY
    }
}

extern "C" void kernel_launch(void* const* d_in, const int* in_sizes, int n_in,
                              void* d_out, int out_size, void* d_ws, size_t ws_size,
                              hipStream_t stream) {
    const float* S = reinterpret_cast<const float*>(d_in[0]);
    float* out = reinterpret_cast<float*>(d_out);
    const int nmat = in_sizes[0] / (NN * NN);   // 128 for (8,16,512,512)

    // ws layout: [flags: NITER*2*nmat ints][pad to 64KB][xdata: NITER*2*nmat*NN floats]
    int* flags = reinterpret_cast<int*>(d_ws);
    float* xdata = reinterpret_cast<float*>(reinterpret_cast<char*>(d_ws) + (64 << 10));

    dim3 grid(2 * nmat);
    dim3 block(512);
    void* args[] = { (void*)&S, (void*)&out, (void*)&flags, (void*)&xdata, (void*)&nmat };
    (void)hipLaunchCooperativeKernel(reinterpret_cast<const void*>(&sinkhorn_pair),
                                     grid, block, args, 0, stream);
}

// Round 7
// 930.167 us; speedup vs baseline: 1.3521x; 1.3521x over previous
//
#include <hip/hip_runtime.h>
#include <hip/hip_fp16.h>

#define NN 512
#define NW 16              // waves per block (1024 threads)
#define RREG 24            // register rows per wave (384 total)
#define RLDS 8             // LDS rows per wave (128 total)
#define REG_ROWS (NW * RREG)   // 384
#define NITER 10

union H2U { uint32_t u; __half2 h; };

__device__ __forceinline__ float wave_reduce_sum(float v) {
    #pragma unroll
    for (int off = 32; off > 0; off >>= 1)
        v += __shfl_xor(v, off, 64);
    return v;   // all 64 lanes hold the sum
}

__device__ __forceinline__ uint4 pack8(const float e[8]) {
    H2U a, b, c, d;
    a.h = __floats2half2_rn(e[0], e[1]);
    b.h = __floats2half2_rn(e[2], e[3]);
    c.h = __floats2half2_rn(e[4], e[5]);
    d.h = __floats2half2_rn(e[6], e[7]);
    return make_uint4(a.u, b.u, c.u, d.u);
}

__device__ __forceinline__ void unpack8(uint4 q, float e[8]) {
    H2U u; float2 f;
    u.u = q.x; f = __half22float2(u.h); e[0] = f.x; e[1] = f.y;
    u.u = q.y; f = __half22float2(u.h); e[2] = f.x; e[3] = f.y;
    u.u = q.z; f = __half22float2(u.h); e[4] = f.x; e[5] = f.y;
    u.u = q.w; f = __half22float2(u.h); e[6] = f.x; e[7] = f.y;
}

// Sync-free design (R2-R6 lesson: every cross-block sync flavor costs ~700us
// total; the only fast structure was block==matrix). One 1024-thread block
// owns a full 512x512 matrix, so row AND col sums are block-local. E=exp(S)
// fp16: 384 rows in 24 NAMED uint4 regs/thread (96 VGPR; 1024-thr block =>
// hard 128-VGPR cap), 128 rows in LDS (128 KB). Fused sweep per iteration:
// A_i = 1/dot(E_i, B) (wave butterfly), col partials c_j += E_ij*A_i; col
// sums completed by a deterministic two-phase LDS tree across 16 waves.
// HBM traffic = read S once + write out once.
#define E_ROWS(M) M(0) M(1) M(2) M(3) M(4) M(5) M(6) M(7) \
                  M(8) M(9) M(10) M(11) M(12) M(13) M(14) M(15) \
                  M(16) M(17) M(18) M(19) M(20) M(21) M(22) M(23)

__global__ __launch_bounds__(1024, 1)
void sinkhorn_block(const float* __restrict__ Sg,
                    float* __restrict__ outg) {
    const int mat = blockIdx.x;
    const size_t base = (size_t)mat * NN * NN;
    const float* S = Sg + base;
    float* out = outg + base;

    __shared__ uint32_t Elds[NW * RLDS][NN / 2];  // fp16x2 rows 384..511 (128 KB)
    __shared__ float part[8][NN];                 // col-partial tree (16 KB)
    __shared__ float Bv[NN];                      // 1/col-sums
    __shared__ float Av[NN];                      // 1/row-sums

    const int tid  = threadIdx.x;
    const int lane = tid & 63;
    const int w    = tid >> 6;

    #define DECL_E(rr) uint4 E##rr;
    E_ROWS(DECL_E)
    #undef DECL_E

    float c[8] = {0.f, 0.f, 0.f, 0.f, 0.f, 0.f, 0.f, 0.f};

    // ---- pass 0: E = exp(S); A = 1/rowsum (B=1); col partials with A ----
    #define PASS0_BODY(gr, STORE) { \
        const float4* p = reinterpret_cast<const float4*>(S + (size_t)(gr) * NN + lane * 8); \
        float4 x0 = p[0], x1 = p[1]; \
        float e[8]; \
        e[0] = __expf(x0.x); e[1] = __expf(x0.y); e[2] = __expf(x0.z); e[3] = __expf(x0.w); \
        e[4] = __expf(x1.x); e[5] = __expf(x1.y); e[6] = __expf(x1.z); e[7] = __expf(x1.w); \
        STORE; \
        float rs = wave_reduce_sum(((e[0]+e[1])+(e[2]+e[3]))+((e[4]+e[5])+(e[6]+e[7]))); \
        const float a = 1.0f / rs; \
        if (lane == 0) Av[gr] = a; \
        c[0] += e[0]*a; c[1] += e[1]*a; c[2] += e[2]*a; c[3] += e[3]*a; \
        c[4] += e[4]*a; c[5] += e[5]*a; c[6] += e[6]*a; c[7] += e[7]*a; }

    #define PASS0_REG(rr) PASS0_BODY(w * RREG + rr, E##rr = pack8(e))
    E_ROWS(PASS0_REG)
    #undef PASS0_REG

    #pragma unroll
    for (int rr = 0; rr < RLDS; ++rr) {
        const int lrl = w * RLDS + rr;    // 0..127
        PASS0_BODY(REG_ROWS + lrl,
                   *reinterpret_cast<uint4*>(&Elds[lrl][lane * 4]) = pack8(e))
    }
    #undef PASS0_BODY

    // ---- per iteration: finish col sums (two-phase wave tree) -> Bv; fused sweep ----
    for (int t = 0; t < NITER; ++t) {
        // phase A: waves 0..7 store their col partials
        if (w < 8) {
            *reinterpret_cast<float4*>(&part[w][lane * 8])     = make_float4(c[0], c[1], c[2], c[3]);
            *reinterpret_cast<float4*>(&part[w][lane * 8 + 4]) = make_float4(c[4], c[5], c[6], c[7]);
        }
        __syncthreads();
        // phase B: waves 8..15 add theirs (disjoint rows -> deterministic)
        if (w >= 8) {
            float4 t0 = *reinterpret_cast<float4*>(&part[w - 8][lane * 8]);
            float4 t1 = *reinterpret_cast<float4*>(&part[w - 8][lane * 8 + 4]);
            t0.x += c[0]; t0.y += c[1]; t0.z += c[2]; t0.w += c[3];
            t1.x += c[4]; t1.y += c[5]; t1.z += c[6]; t1.w += c[7];
            *reinterpret_cast<float4*>(&part[w - 8][lane * 8])     = t0;
            *reinterpret_cast<float4*>(&part[w - 8][lane * 8 + 4]) = t1;
        }
        __syncthreads();
        // phase C: fold 8 rows -> Bv
        if (tid < NN) {
            float s = 0.f;
            #pragma unroll
            for (int k = 0; k < 8; ++k) s += part[k][tid];
            Bv[tid] = 1.0f / s;
        }
        __syncthreads();

        if (t == NITER - 1) break;        // B^(10) done; A^(10) already in Av

        // ---- fused sweep: A_i = 1/dot(E_i, B); c_j += E_ij * A_i ----
        float b[8];
        #pragma unroll
        for (int k = 0; k < 8; ++k) b[k] = Bv[lane * 8 + k];
        #pragma unroll
        for (int k = 0; k < 8; ++k) c[k] = 0.f;

        #define SWEEP_BODY(gr, LOADQ) { \
            uint4 q = (LOADQ); \
            float e[8]; unpack8(q, e); \
            float d = ((e[0]*b[0] + e[1]*b[1]) + (e[2]*b[2] + e[3]*b[3])) + \
                      ((e[4]*b[4] + e[5]*b[5]) + (e[6]*b[6] + e[7]*b[7])); \
            d = wave_reduce_sum(d); \
            const float a = 1.0f / d; \
            if (lane == 0) Av[gr] = a; \
            c[0] += e[0]*a; c[1] += e[1]*a; c[2] += e[2]*a; c[3] += e[3]*a; \
            c[4] += e[4]*a; c[5] += e[5]*a; c[6] += e[6]*a; c[7] += e[7]*a; }

        #define SWEEP_REG(rr) SWEEP_BODY(w * RREG + rr, E##rr)
        E_ROWS(SWEEP_REG)
        #undef SWEEP_REG

        #pragma unroll
        for (int rr = 0; rr < RLDS; ++rr) {
            const int lrl = w * RLDS + rr;
            SWEEP_BODY(REG_ROWS + lrl,
                       *reinterpret_cast<const uint4*>(&Elds[lrl][lane * 4]))
        }
        #undef SWEEP_BODY
        __syncthreads();   // part[] reads (phase C) done before next phase A overwrite
    }

    // ---- final: out_ij = E_ij * A_i * B_j ----
    {
        float b[8];
        #pragma unroll
        for (int k = 0; k < 8; ++k) b[k] = Bv[lane * 8 + k];

        #define FINAL_BODY(gr, LOADQ) { \
            uint4 q = (LOADQ); \
            float e[8]; unpack8(q, e); \
            const float a = Av[gr]; \
            float* op = out + (size_t)(gr) * NN + lane * 8; \
            reinterpret_cast<float4*>(op)[0] = \
                make_float4(e[0]*a*b[0], e[1]*a*b[1], e[2]*a*b[2], e[3]*a*b[3]); \
            reinterpret_cast<float4*>(op)[1] = \
                make_float4(e[4]*a*b[4], e[5]*a*b[5], e[6]*a*b[6], e[7]*a*b[7]); }

        #define FINAL_REG(rr) FINAL_BODY(w * RREG + rr, E##rr)
        E_ROWS(FINAL_REG)
        #undef FINAL_REG

        #pragma unroll
        for (int rr = 0; rr < RLDS; ++rr) {
            const int lrl = w * RLDS + rr;
            FINAL_BODY(REG_ROWS + lrl,
                       *reinterpret_cast<const uint4*>(&Elds[lrl][lane * 4]))
        }
        #undef FINAL_BODY
    }
}

extern "C" void kernel_launch(void* const* d_in, const int* in_sizes, int n_in,
                              void* d_out, int out_size, void* d_ws, size_t ws_size,
                              hipStream_t stream) {
    const float* S = reinterpret_cast<const float*>(d_in[0]);
    float* out = reinterpret_cast<float*>(d_out);
    const int nmat = in_sizes[0] / (NN * NN);   // 128 for (8,16,512,512)

    sinkhorn_block<<<dim3(nmat), dim3(1024), 0, stream>>>(S, out);
}

// Round 8
// 255.694 us; speedup vs baseline: 4.9187x; 3.6378x over previous
//
#include <hip/hip_runtime.h>
#include <hip/hip_fp16.h>

#define NN 512
#define NBLK 16            // blocks per matrix
#define BROWS 32           // rows per block
#define THREADS 256        // 4 waves
#define NWAVE 4
#define NITER 10

union H2U { uint32_t u; __half2 h; };

__device__ __forceinline__ float wave_reduce_sum(float v) {
    #pragma unroll
    for (int off = 32; off > 0; off >>= 1)
        v += __shfl_xor(v, off, 64);
    return v;   // all 64 lanes hold the sum
}

__device__ __forceinline__ uint4 pack8(const float e[8]) {
    H2U a, b, c, d;
    a.h = __floats2half2_rn(e[0], e[1]);
    b.h = __floats2half2_rn(e[2], e[3]);
    c.h = __floats2half2_rn(e[4], e[5]);
    d.h = __floats2half2_rn(e[6], e[7]);
    return make_uint4(a.u, b.u, c.u, d.u);
}

__device__ __forceinline__ void unpack8(uint4 q, float e[8]) {
    H2U u; float2 f;
    u.u = q.x; f = __half22float2(u.h); e[0] = f.x; e[1] = f.y;
    u.u = q.y; f = __half22float2(u.h); e[2] = f.x; e[3] = f.y;
    u.u = q.z; f = __half22float2(u.h); e[4] = f.x; e[5] = f.y;
    u.u = q.w; f = __half22float2(u.h); e[6] = f.x; e[7] = f.y;
}

// Row of E (8 elems/lane): from packed-fp16 workspace, or recomputed exp(S).
template<bool USE_E>
__device__ __forceinline__ void load_row8(const uint32_t* __restrict__ E32,
                                          const float* __restrict__ S,
                                          size_t row_g, int lane, float e[8]) {
    if constexpr (USE_E) {
        uint4 q = *reinterpret_cast<const uint4*>(E32 + row_g * (NN / 2) + lane * 4);
        unpack8(q, e);
    } else {
        const float4* p = reinterpret_cast<const float4*>(S + row_g * NN + lane * 8);
        float4 x0 = p[0], x1 = p[1];
        e[0] = __expf(x0.x); e[1] = __expf(x0.y); e[2] = __expf(x0.z); e[3] = __expf(x0.w);
        e[4] = __expf(x1.x); e[5] = __expf(x1.y); e[6] = __expf(x1.z); e[7] = __expf(x1.w);
    }
}

// Streaming multi-kernel Sinkhorn (R2-R7 lesson: compiler spills any big
// per-thread state; cross-block spin sync was never clean). Iteration
// barrier = kernel boundary (graph replay). Small 256-thr blocks, ~48 VGPR,
// 8 waves/SIMD, all 256 CUs. Block = 32 rows of one matrix. Per sweep:
// B from prev partials (redundant per-block reduce, L2-hot), per row
// A_i = 1/dot(E_i,B) (wave butterfly), col partials -> LDS -> global
// (parity double-buffered: read pr, write pw -> no intra-kernel race).

template<bool USE_E>
__global__ __launch_bounds__(THREADS)
void k_first(const float* __restrict__ S, uint32_t* __restrict__ E32,
             float* __restrict__ A, float* __restrict__ pw) {
    const int m = blockIdx.x >> 4, blk = blockIdx.x & 15;
    const int lane = threadIdx.x & 63, w = threadIdx.x >> 6;
    __shared__ float part[NWAVE][NN];

    float c[8] = {0.f, 0.f, 0.f, 0.f, 0.f, 0.f, 0.f, 0.f};
    #pragma unroll
    for (int r = 0; r < 8; ++r) {
        const size_t row_g = (size_t)m * NN + blk * BROWS + w * 8 + r;
        const float4* p = reinterpret_cast<const float4*>(S + row_g * NN + lane * 8);
        float4 x0 = p[0], x1 = p[1];
        float e[8];
        e[0] = __expf(x0.x); e[1] = __expf(x0.y); e[2] = __expf(x0.z); e[3] = __expf(x0.w);
        e[4] = __expf(x1.x); e[5] = __expf(x1.y); e[6] = __expf(x1.z); e[7] = __expf(x1.w);
        if constexpr (USE_E)
            *reinterpret_cast<uint4*>(E32 + row_g * (NN / 2) + lane * 4) = pack8(e);
        float rs = wave_reduce_sum(((e[0]+e[1])+(e[2]+e[3]))+((e[4]+e[5])+(e[6]+e[7])));
        const float a = 1.0f / rs;
        if (lane == 0) A[row_g] = a;
        #pragma unroll
        for (int k = 0; k < 8; ++k) c[k] += e[k] * a;
    }
    *reinterpret_cast<float4*>(&part[w][lane * 8])     = make_float4(c[0], c[1], c[2], c[3]);
    *reinterpret_cast<float4*>(&part[w][lane * 8 + 4]) = make_float4(c[4], c[5], c[6], c[7]);
    __syncthreads();
    for (int j = threadIdx.x; j < NN; j += THREADS)
        pw[((size_t)m * NBLK + blk) * NN + j] =
            (part[0][j] + part[1][j]) + (part[2][j] + part[3][j]);
}

template<bool USE_E>
__global__ __launch_bounds__(THREADS)
void k_sweep(const uint32_t* __restrict__ E32, const float* __restrict__ S,
             const float* __restrict__ pr, float* __restrict__ pw,
             float* __restrict__ A) {
    const int m = blockIdx.x >> 4, blk = blockIdx.x & 15;
    const int lane = threadIdx.x & 63, w = threadIdx.x >> 6;
    __shared__ float Bsh[NN];
    __shared__ float part[NWAVE][NN];

    // B-phase: complete col sums of previous sweep (fixed order, deterministic)
    for (int j = threadIdx.x; j < NN; j += THREADS) {
        float s = 0.f;
        #pragma unroll
        for (int k = 0; k < NBLK; ++k) s += pr[((size_t)m * NBLK + k) * NN + j];
        Bsh[j] = 1.0f / s;
    }
    __syncthreads();

    float b[8];
    #pragma unroll
    for (int k = 0; k < 8; ++k) b[k] = Bsh[lane * 8 + k];
    float c[8] = {0.f, 0.f, 0.f, 0.f, 0.f, 0.f, 0.f, 0.f};

    #pragma unroll
    for (int r = 0; r < 8; ++r) {
        const size_t row_g = (size_t)m * NN + blk * BROWS + w * 8 + r;
        float e[8];
        load_row8<USE_E>(E32, S, row_g, lane, e);
        float d = ((e[0]*b[0] + e[1]*b[1]) + (e[2]*b[2] + e[3]*b[3])) +
                  ((e[4]*b[4] + e[5]*b[5]) + (e[6]*b[6] + e[7]*b[7]));
        d = wave_reduce_sum(d);
        const float a = 1.0f / d;
        if (lane == 0) A[row_g] = a;
        #pragma unroll
        for (int k = 0; k < 8; ++k) c[k] += e[k] * a;
    }
    *reinterpret_cast<float4*>(&part[w][lane * 8])     = make_float4(c[0], c[1], c[2], c[3]);
    *reinterpret_cast<float4*>(&part[w][lane * 8 + 4]) = make_float4(c[4], c[5], c[6], c[7]);
    __syncthreads();
    for (int j = threadIdx.x; j < NN; j += THREADS)
        pw[((size_t)m * NBLK + blk) * NN + j] =
            (part[0][j] + part[1][j]) + (part[2][j] + part[3][j]);
}

template<bool USE_E>
__global__ __launch_bounds__(THREADS)
void k_final(const uint32_t* __restrict__ E32, const float* __restrict__ S,
             const float* __restrict__ pr, const float* __restrict__ A,
             float* __restrict__ out) {
    const int m = blockIdx.x >> 4, blk = blockIdx.x & 15;
    const int lane = threadIdx.x & 63, w = threadIdx.x >> 6;
    __shared__ float Bsh[NN];

    for (int j = threadIdx.x; j < NN; j += THREADS) {
        float s = 0.f;
        #pragma unroll
        for (int k = 0; k < NBLK; ++k) s += pr[((size_t)m * NBLK + k) * NN + j];
        Bsh[j] = 1.0f / s;
    }
    __syncthreads();

    float b[8];
    #pragma unroll
    for (int k = 0; k < 8; ++k) b[k] = Bsh[lane * 8 + k];

    #pragma unroll
    for (int r = 0; r < 8; ++r) {
        const size_t row_g = (size_t)m * NN + blk * BROWS + w * 8 + r;
        const float a = A[row_g];
        float e[8];
        load_row8<USE_E>(E32, S, row_g, lane, e);
        float* op = out + row_g * NN + lane * 8;
        reinterpret_cast<float4*>(op)[0] =
            make_float4(e[0]*a*b[0], e[1]*a*b[1], e[2]*a*b[2], e[3]*a*b[3]);
        reinterpret_cast<float4*>(op)[1] =
            make_float4(e[4]*a*b[4], e[5]*a*b[5], e[6]*a*b[6], e[7]*a*b[7]);
    }
}

extern "C" void kernel_launch(void* const* d_in, const int* in_sizes, int n_in,
                              void* d_out, int out_size, void* d_ws, size_t ws_size,
                              hipStream_t stream) {
    const float* S = reinterpret_cast<const float*>(d_in[0]);
    float* out = reinterpret_cast<float*>(d_out);
    const int nmat = in_sizes[0] / (NN * NN);   // 128 for (8,16,512,512)

    const size_t e_bytes   = (size_t)in_sizes[0] * 2;            // fp16 E
    const size_t pa_floats = (size_t)nmat * NBLK * NN;           // one partial buffer
    const size_t need      = e_bytes + (2 * pa_floats + (size_t)nmat * NN) * 4;

    dim3 g(nmat * NBLK), b(THREADS);
    if (d_ws != nullptr && ws_size >= need) {
        uint32_t* E32 = reinterpret_cast<uint32_t*>(d_ws);
        float* p0 = reinterpret_cast<float*>(reinterpret_cast<char*>(d_ws) + e_bytes);
        float* p1 = p0 + pa_floats;
        float* A  = p1 + pa_floats;
        k_first<true><<<g, b, 0, stream>>>(S, E32, A, p0);
        for (int t = 1; t < NITER; ++t)
            k_sweep<true><<<g, b, 0, stream>>>(E32, S, (t & 1) ? p0 : p1,
                                               (t & 1) ? p1 : p0, A);
        k_final<true><<<g, b, 0, stream>>>(E32, S, p1, A, out);   // t=9 wrote p1
    } else {
        // fallback: recompute exp(S) per sweep, only partials+A in ws
        float* p0 = reinterpret_cast<float*>(d_ws);
        float* p1 = p0 + pa_floats;
        float* A  = p1 + pa_floats;
        k_first<false><<<g, b, 0, stream>>>(S, nullptr, A, p0);
        for (int t = 1; t < NITER; ++t)
            k_sweep<false><<<g, b, 0, stream>>>(nullptr, S, (t & 1) ? p0 : p1,
                                                (t & 1) ? p1 : p0, A);
        k_final<false><<<g, b, 0, stream>>>(nullptr, S, p1, A, out);
    }
}